// Round 4
// baseline (2806.766 us; speedup 1.0000x reference)
//
#include <hip/hip_runtime.h>
#include <hip/hip_bf16.h>

typedef unsigned int u32;

#define N_NODE_ 500
#define N_POD_  20000
#define N_SVC_  2000
#define N_TOT_  22500
#define T_ 16
#define F_ 64
#define H_ 128
#define O_ 64

// ---------------- static device scratch (no d_ws use) ----------------
// float region
#define OF_OUTD_SC  0
#define OF_IND_SC   2000
#define OF_OUTD_IN  4000
#define OF_IND_IN   24000
#define OF_OUTD_NI  24500
#define OF_IND_NI   25000
#define OF_OUTD_II  45000
#define OF_IND_II   65000
#define OF_OUTD_SI  85000
#define OF_IND_SI   87000
#define OF_OUTD_IS  107000
#define OF_IND_IS   127000
#define OF_DEG_END  129000
#define OF_WIHT0    129024
#define OF_WHHT0    (129024 + 32768)
#define OF_WIHT1    (129024 + 49152)
#define OF_WHHT1    (129024 + 65536)
#define G_F_SIZE    (129024 + 81920)
// int region (cnt doubles as fill cursor after re-zero)
#define OI_CNT_IN 0
#define OI_CNT_NI 500
#define OI_CNT_II 20500
#define OI_CNT_SI 40500
#define OI_CNT_SC 60500
#define OI_CNT_IS 62500
#define OI_CNT_END 64500
#define OI_OFF_IN 64500
#define OI_OFF_NI 65001
#define OI_OFF_II 85002
#define OI_OFF_SI 105003
#define OI_OFF_SC 125004
#define OI_OFF_IS 127005
#define OI_CSR_IN 129006
#define OI_CSR_NI 149006
#define OI_CSR_II 169006
#define OI_CSR_SI 269006
#define OI_CSR_SC 289006
#define OI_CSR_IS 305006
#define G_I_SIZE  325006

__device__ float g_f[G_F_SIZE];
__device__ int g_i[G_I_SIZE];

__device__ __forceinline__ float sigf(float x) { return 1.0f / (1.0f + __expf(-x)); }

// ---------- zero the accumulated scratch regions (every launch) ----------
__global__ void zero_k() {
  int i = blockIdx.x * 256 + threadIdx.x;
  if (i < OF_DEG_END + 24) g_f[i] = 0.0f;
  if (i < OI_CNT_END) g_i[i] = 0;
}

__global__ void zero_cnt_k() {
  int i = blockIdx.x * 256 + threadIdx.x;
  if (i < OI_CNT_END) g_i[i] = 0;
}

// ---------- per-relation degrees + in-counts ----------
__global__ void deg_cnt_k(const int* __restrict__ src, const int* __restrict__ dst, int n,
                          int o_outd, int o_ind, int o_cnt) {
  int e = blockIdx.x * 256 + threadIdx.x;
  if (e < n) {
    atomicAdd(&g_f[o_outd + src[e]], 1.0f);
    atomicAdd(&g_f[o_ind + dst[e]], 1.0f);
    atomicAdd(&g_i[o_cnt + dst[e]], 1);
  }
}

__global__ void rsqrt_deg_k() {
  int i = blockIdx.x * 256 + threadIdx.x;
  if (i < OF_DEG_END) g_f[i] = rsqrtf(fmaxf(g_f[i], 1.0f));
}

// fp32 [R,C] -> fp32 [C,R] into g_f[o_out..]
__global__ void transpose_w_k(const float* __restrict__ in, int o_out, int R, int C) {
  int i = blockIdx.x * 256 + threadIdx.x;
  if (i < R * C) {
    int r = i / C, c = i - r * C;
    g_f[o_out + c * R + r] = in[i];
  }
}

// ---------- 6 single-block exclusive scans ----------
__global__ void exscan6_k() {
  const int cnto[6] = {OI_CNT_IN, OI_CNT_NI, OI_CNT_II, OI_CNT_SI, OI_CNT_SC, OI_CNT_IS};
  const int offo[6] = {OI_OFF_IN, OI_OFF_NI, OI_OFF_II, OI_OFF_SI, OI_OFF_SC, OI_OFF_IS};
  const int ns[6] = {500, 20000, 20000, 20000, 2000, 2000};
  int rel = blockIdx.x;
  const int* cnt = g_i + cnto[rel];
  int* off = g_i + offo[rel];
  int n = ns[rel];
  __shared__ int base_s[257];
  __shared__ int part[256];
  int tid = threadIdx.x;
  int chunk = (n + 255) >> 8;
  int lo = tid * chunk;
  int hi = lo + chunk; if (hi > n) hi = n;
  int s = 0;
  for (int i = lo; i < hi; ++i) s += cnt[i];
  part[tid] = s;
  __syncthreads();
  if (tid == 0) {
    int run = 0;
    for (int j = 0; j < 256; ++j) { base_s[j] = run; run += part[j]; }
    base_s[256] = run;
  }
  __syncthreads();
  int run = base_s[tid];
  for (int i = lo; i < hi; ++i) { off[i] = run; run += cnt[i]; }
  if (tid == 0) off[n] = base_s[256];
}

__global__ void fill_csr_k(const int* __restrict__ src, const int* __restrict__ dst, int n,
                           int o_off, int o_cur, int o_csr) {
  int e = blockIdx.x * 256 + threadIdx.x;
  if (e < n) {
    int d = dst[e];
    int p = atomicAdd(&g_i[o_cur + d], 1);
    g_i[o_csr + g_i[o_off + d] + p] = src[e];
  }
}

// ---------- fused gather + GEMM per dst node ----------
// block = one dst node; 256 threads; out[t][h] = relu(scale*(sum_rel m_rel*rsqrt(ind)*W_rel + b_rel))
template <int NREL>
__global__ __launch_bounds__(256) void gconv_gather_k(
    const float* __restrict__ x0, const float* __restrict__ x1, const float* __restrict__ x2,
    int off0, int off1, int off2, int csr0, int csr1, int csr2,
    int od0, int od1, int od2, int id0, int id1, int id2,
    const float* __restrict__ W0, const float* __restrict__ W1, const float* __restrict__ W2,
    const float* __restrict__ b0, const float* __restrict__ b1, const float* __restrict__ b2,
    float scale, float* __restrict__ outp) {
  const float* xs_[3] = {x0, x1, x2};
  const int offs[3] = {off0, off1, off2};
  const int csrs[3] = {csr0, csr1, csr2};
  const int ods[3] = {od0, od1, od2};
  const int ids[3] = {id0, id1, id2};
  const float* Ws[3] = {W0, W1, W2};
  const float* bs[3] = {b0, b1, b2};

  int node = blockIdx.x;
  int tid = threadIdx.x;
  int c = tid & 127;
  int rg = tid >> 7;  // 0/1 -> t rows [0,8) / [8,16)
  __shared__ float msh[T_][F_];  // flat index = t*64+f

  float bb = 0.0f;
#pragma unroll
  for (int rel = 0; rel < NREL; ++rel) bb += bs[rel][c];
  float acc[8];
#pragma unroll
  for (int i = 0; i < 8; ++i) acc[i] = bb;

#pragma unroll
  for (int rel = 0; rel < NREL; ++rel) {
    int e0 = g_i[offs[rel] + node], e1 = g_i[offs[rel] + node + 1];
    const int* csr = g_i + csrs[rel];
    const float* od = g_f + ods[rel];
    const float* xr = xs_[rel];
    // thread owns 4 contiguous elements of the 1024-float [T,F] row
    float a0 = 0.0f, a1 = 0.0f, a2 = 0.0f, a3 = 0.0f;
    for (int e = e0; e < e1; ++e) {
      int s = csr[e];
      float rs = od[s];
      float4 v = ((const float4*)(xr + (size_t)s * 1024))[tid];
      a0 += v.x * rs;
      a1 += v.y * rs;
      a2 += v.z * rs;
      a3 += v.w * rs;
    }
    __syncthreads();  // previous rel's GEMM reads done
    float* mf = &msh[0][0];
    mf[tid * 4 + 0] = a0;
    mf[tid * 4 + 1] = a1;
    mf[tid * 4 + 2] = a2;
    mf[tid * 4 + 3] = a3;
    __syncthreads();
    float rind = g_f[ids[rel] + node];
    const float* W = Ws[rel];
#pragma unroll 4
    for (int f = 0; f < F_; ++f) {
      float w = W[f * H_ + c] * rind;
#pragma unroll
      for (int i = 0; i < 8; ++i) acc[i] += msh[rg * 8 + i][f] * w;
    }
  }
  float* o = outp + (size_t)node * (T_ * H_);
#pragma unroll
  for (int i = 0; i < 8; ++i) {
    float v = acc[i] * scale;
    o[(rg * 8 + i) * H_ + c] = fmaxf(v, 0.0f);
  }
}

// ---------- full 2-layer LSTM over all T (batch-parallel, state in LDS) ----------
#define RB 16
__global__ __launch_bounds__(256) void lstm_all_k(
    const float* __restrict__ feat,  // [N_TOT,16,128] fp32 (post-relu)
    const float* __restrict__ bih0, const float* __restrict__ bhh0,
    const float* __restrict__ bih1, const float* __restrict__ bhh1,
    float* __restrict__ out2) {
  const float* WihT0 = g_f + OF_WIHT0;
  const float* WhhT0 = g_f + OF_WHHT0;
  const float* WihT1 = g_f + OF_WIHT1;
  const float* WhhT1 = g_f + OF_WHHT1;
  int b0 = blockIdx.x * RB;
  int idx = threadIdx.x;
  __shared__ float xs[RB][H_];    // 8 KB
  __shared__ float gs[RB][256];   // 16 KB
  __shared__ float hs0[RB][O_], cs0[RB][O_], hs1[RB][O_], cs1[RB][O_];  // 16 KB

  for (int j = idx; j < RB * O_; j += 256) {
    int r = j >> 6, k = j & 63;
    hs0[r][k] = 0.0f; cs0[r][k] = 0.0f; hs1[r][k] = 0.0f; cs1[r][k] = 0.0f;
  }
  float bb0 = bih0[idx] + bhh0[idx];
  float bb1 = bih1[idx] + bhh1[idx];

  for (int t = 0; t < T_; ++t) {
    __syncthreads();  // protect xs/hs/cs from previous-iteration readers
    for (int j = idx; j < RB * H_; j += 256) {
      int r = j >> 7, k = j & 127;
      int gb = b0 + r;
      xs[r][k] = (gb < N_TOT_) ? feat[((size_t)gb * T_ + t) * H_ + k] : 0.0f;
    }
    __syncthreads();

    float acc[RB];
    // layer 0 gates: g[idx] = bb0 + sum_k xs[k]*Wih0[idx,k] + sum_k hs0[k]*Whh0[idx,k]
#pragma unroll
    for (int r = 0; r < RB; ++r) acc[r] = bb0;
#pragma unroll 4
    for (int k = 0; k < H_; ++k) {
      float w = WihT0[k * 256 + idx];
#pragma unroll
      for (int r = 0; r < RB; ++r) acc[r] += xs[r][k] * w;
    }
#pragma unroll 4
    for (int k = 0; k < O_; ++k) {
      float w = WhhT0[k * 256 + idx];
#pragma unroll
      for (int r = 0; r < RB; ++r) acc[r] += hs0[r][k] * w;
    }
#pragma unroll
    for (int r = 0; r < RB; ++r) gs[r][idx] = acc[r];
    __syncthreads();

    // layer 0 cell update
    for (int item = idx; item < RB * O_; item += 256) {
      int r = item >> 6, j = item & 63;
      float iv = sigf(gs[r][j]);
      float fv = sigf(gs[r][64 + j]);
      float gv = tanhf(gs[r][128 + j]);
      float ov = sigf(gs[r][192 + j]);
      float cc = fv * cs0[r][j] + iv * gv;
      float hh = ov * tanhf(cc);
      cs0[r][j] = cc;
      hs0[r][j] = hh;
    }
    __syncthreads();

    // layer 1 gates
#pragma unroll
    for (int r = 0; r < RB; ++r) acc[r] = bb1;
#pragma unroll 4
    for (int k = 0; k < O_; ++k) {
      float w = WihT1[k * 256 + idx];
#pragma unroll
      for (int r = 0; r < RB; ++r) acc[r] += hs0[r][k] * w;
    }
#pragma unroll 4
    for (int k = 0; k < O_; ++k) {
      float w = WhhT1[k * 256 + idx];
#pragma unroll
      for (int r = 0; r < RB; ++r) acc[r] += hs1[r][k] * w;
    }
#pragma unroll
    for (int r = 0; r < RB; ++r) gs[r][idx] = acc[r];
    __syncthreads();

    // layer 1 cell update + output (relu)
    for (int item = idx; item < RB * O_; item += 256) {
      int r = item >> 6, j = item & 63;
      int gb = b0 + r;
      float iv = sigf(gs[r][j]);
      float fv = sigf(gs[r][64 + j]);
      float gv = tanhf(gs[r][128 + j]);
      float ov = sigf(gs[r][192 + j]);
      float cc = fv * cs1[r][j] + iv * gv;
      float hh = ov * tanhf(cc);
      cs1[r][j] = cc;
      hs1[r][j] = hh;
      if (gb < N_TOT_) out2[((size_t)gb * T_ + t) * O_ + j] = fmaxf(hh, 0.0f);
    }
  }
}

extern "C" void kernel_launch(void* const* d_in, const int* in_sizes, int n_in,
                              void* d_out, int out_size, void* d_ws, size_t ws_size,
                              hipStream_t stream) {
  (void)in_sizes; (void)n_in; (void)out_size; (void)d_ws; (void)ws_size;
  const float* x_node = (const float*)d_in[0];
  const float* x_pod  = (const float*)d_in[1];
  const float* x_svc  = (const float*)d_in[2];
  const int* sc_src = (const int*)d_in[3];
  const int* sc_dst = (const int*)d_in[4];
  const int* in_src = (const int*)d_in[5];
  const int* in_dst = (const int*)d_in[6];
  const int* ni_src = (const int*)d_in[7];
  const int* ni_dst = (const int*)d_in[8];
  const int* ii_src = (const int*)d_in[9];
  const int* ii_dst = (const int*)d_in[10];
  const int* si_src = (const int*)d_in[11];
  const int* si_dst = (const int*)d_in[12];
  const int* is_src = (const int*)d_in[13];
  const int* is_dst = (const int*)d_in[14];
  const float* W_sc = (const float*)d_in[15]; const float* b_sc = (const float*)d_in[16];
  const float* W_in = (const float*)d_in[17]; const float* b_in = (const float*)d_in[18];
  const float* W_ni = (const float*)d_in[19]; const float* b_ni = (const float*)d_in[20];
  const float* W_ii = (const float*)d_in[21]; const float* b_ii = (const float*)d_in[22];
  const float* W_si = (const float*)d_in[23]; const float* b_si = (const float*)d_in[24];
  const float* W_is = (const float*)d_in[25]; const float* b_is = (const float*)d_in[26];
  const float* Wih0 = (const float*)d_in[27]; const float* Whh0 = (const float*)d_in[28];
  const float* bih0 = (const float*)d_in[29]; const float* bhh0 = (const float*)d_in[30];
  const float* Wih1 = (const float*)d_in[31]; const float* Whh1 = (const float*)d_in[32];
  const float* bih1 = (const float*)d_in[33]; const float* bhh1 = (const float*)d_in[34];

  float* out_feat = (float*)d_out;
  float* out_h = out_feat + (size_t)N_TOT_ * T_ * H_;  // +46,080,000

  // zero accumulated scratch
  zero_k<<<(OF_DEG_END + 24 + 255) / 256, 256, 0, stream>>>();

  // degrees + counts
  deg_cnt_k<<<(16000 + 255) / 256, 256, 0, stream>>>(sc_src, sc_dst, 16000, OF_OUTD_SC, OF_IND_SC, OI_CNT_SC);
  deg_cnt_k<<<(20000 + 255) / 256, 256, 0, stream>>>(in_src, in_dst, 20000, OF_OUTD_IN, OF_IND_IN, OI_CNT_IN);
  deg_cnt_k<<<(20000 + 255) / 256, 256, 0, stream>>>(ni_src, ni_dst, 20000, OF_OUTD_NI, OF_IND_NI, OI_CNT_NI);
  deg_cnt_k<<<(100000 + 255) / 256, 256, 0, stream>>>(ii_src, ii_dst, 100000, OF_OUTD_II, OF_IND_II, OI_CNT_II);
  deg_cnt_k<<<(20000 + 255) / 256, 256, 0, stream>>>(si_src, si_dst, 20000, OF_OUTD_SI, OF_IND_SI, OI_CNT_SI);
  deg_cnt_k<<<(20000 + 255) / 256, 256, 0, stream>>>(is_src, is_dst, 20000, OF_OUTD_IS, OF_IND_IS, OI_CNT_IS);
  rsqrt_deg_k<<<(OF_DEG_END + 255) / 256, 256, 0, stream>>>();

  // LSTM weight transposes (fp32 [4O,I] -> fp32 [I,4O])
  transpose_w_k<<<(256 * 128 + 255) / 256, 256, 0, stream>>>(Wih0, OF_WIHT0, 256, 128);
  transpose_w_k<<<(256 * 64 + 255) / 256, 256, 0, stream>>>(Whh0, OF_WHHT0, 256, 64);
  transpose_w_k<<<(256 * 64 + 255) / 256, 256, 0, stream>>>(Wih1, OF_WIHT1, 256, 64);
  transpose_w_k<<<(256 * 64 + 255) / 256, 256, 0, stream>>>(Whh1, OF_WHHT1, 256, 64);

  // CSR build
  exscan6_k<<<6, 256, 0, stream>>>();
  zero_cnt_k<<<(OI_CNT_END + 255) / 256, 256, 0, stream>>>();
  fill_csr_k<<<(20000 + 255) / 256, 256, 0, stream>>>(in_src, in_dst, 20000, OI_OFF_IN, OI_CNT_IN, OI_CSR_IN);
  fill_csr_k<<<(20000 + 255) / 256, 256, 0, stream>>>(ni_src, ni_dst, 20000, OI_OFF_NI, OI_CNT_NI, OI_CSR_NI);
  fill_csr_k<<<(100000 + 255) / 256, 256, 0, stream>>>(ii_src, ii_dst, 100000, OI_OFF_II, OI_CNT_II, OI_CSR_II);
  fill_csr_k<<<(20000 + 255) / 256, 256, 0, stream>>>(si_src, si_dst, 20000, OI_OFF_SI, OI_CNT_SI, OI_CSR_SI);
  fill_csr_k<<<(16000 + 255) / 256, 256, 0, stream>>>(sc_src, sc_dst, 16000, OI_OFF_SC, OI_CNT_SC, OI_CSR_SC);
  fill_csr_k<<<(20000 + 255) / 256, 256, 0, stream>>>(is_src, is_dst, 20000, OI_OFF_IS, OI_CNT_IS, OI_CSR_IS);

  // fused gather + GEMM per dst type
  gconv_gather_k<1><<<N_NODE_, 256, 0, stream>>>(
      x_pod, nullptr, nullptr, OI_OFF_IN, 0, 0, OI_CSR_IN, 0, 0,
      OF_OUTD_IN, 0, 0, OF_IND_IN, 0, 0,
      W_in, nullptr, nullptr, b_in, nullptr, nullptr, 1.0f, out_feat);
  gconv_gather_k<3><<<N_POD_, 256, 0, stream>>>(
      x_node, x_pod, x_svc, OI_OFF_NI, OI_OFF_II, OI_OFF_SI, OI_CSR_NI, OI_CSR_II, OI_CSR_SI,
      OF_OUTD_NI, OF_OUTD_II, OF_OUTD_SI, OF_IND_NI, OF_IND_II, OF_IND_SI,
      W_ni, W_ii, W_si, b_ni, b_ii, b_si, 1.0f / 3.0f,
      out_feat + (size_t)N_NODE_ * (T_ * H_));
  gconv_gather_k<2><<<N_SVC_, 256, 0, stream>>>(
      x_svc, x_pod, nullptr, OI_OFF_SC, OI_OFF_IS, 0, OI_CSR_SC, OI_CSR_IS, 0,
      OF_OUTD_SC, OF_OUTD_IS, 0, OF_IND_SC, OF_IND_IS, 0,
      W_sc, W_is, nullptr, b_sc, b_is, nullptr, 0.5f,
      out_feat + (size_t)(N_NODE_ + N_POD_) * (T_ * H_));

  // 2-layer LSTM, whole sequence in one kernel
  lstm_all_k<<<(N_TOT_ + RB - 1) / RB, 256, 0, stream>>>(
      out_feat, bih0, bhh0, bih1, bhh1, out_h);
}